// Round 4
// baseline (996.481 us; speedup 1.0000x reference)
//
#include <hip/hip_runtime.h>
#include <hip/hip_bf16.h>

#define BB 256
#define LL 1024
#define EE 128
#define HH 256
#define VV 64

typedef short bf16x8 __attribute__((ext_vector_type(8)));
typedef float f32x4 __attribute__((ext_vector_type(4)));
typedef float v4f  __attribute__((ext_vector_type(4)));

// ws layout (bytes):
//   [0,      65536)   table f32 [64][256]: b_e[j]+b_h[j]+dot(emb[v],W_e[j])
//   [65536, 196608)   W_h B-frags bf16: frag f=nt*8+kt (nt<16,kt<8), 1024B each,
//                     elem (l,i) = W_h[16nt+(l&15)][32kt+8*(l>>4)+i]
//   [196608,229376)   fc hi frags (nt<4): fc_w[16nt+(l&15)][32kt+8*(l>>4)+i] hi
//   [229376,262144)   fc lo frags (residual)

__device__ __forceinline__ unsigned short f2bf(float v) {
    __hip_bfloat16 h = __float2bfloat16(v);
    return *reinterpret_cast<unsigned short*>(&h);
}
__device__ __forceinline__ float bf2f(unsigned short u) {
    __hip_bfloat16 h = *reinterpret_cast<__hip_bfloat16*>(&u);
    return __bfloat162float(h);
}

__global__ void prep_kernel(const float* __restrict__ emb,
                            const float* __restrict__ W_e,
                            const float* __restrict__ b_e,
                            const float* __restrict__ W_h,
                            const float* __restrict__ b_h,
                            const float* __restrict__ fc_w,
                            float* __restrict__ ws) {
    int t = blockIdx.x * 256 + threadIdx.x;  // 0..26623
    if (t < 16384) {
        int v = t >> 8, j = t & 255;
        float s = b_e[j] + b_h[j];
        const v4f* ev = (const v4f*)(emb + v * EE);
        const v4f* wr = (const v4f*)(W_e + j * EE);
#pragma unroll
        for (int e = 0; e < EE / 4; ++e) {
            v4f a = ev[e], c = wr[e];
            s += a.x * c.x + a.y * c.y + a.z * c.z + a.w * c.w;
        }
        ws[t] = s;
    } else if (t < 24576) {
        int q = t - 16384;            // 0..8191
        int f = q >> 6, l = q & 63;   // frag id, lane
        int nt = f >> 3, kt = f & 7;
        int row = 16 * nt + (l & 15);
        int k0 = 32 * kt + 8 * (l >> 4);
        unsigned short* p = (unsigned short*)((char*)ws + 65536 + f * 1024 + l * 16);
#pragma unroll
        for (int i = 0; i < 8; ++i) p[i] = f2bf(W_h[row * HH + k0 + i]);
    } else {
        int q = t - 24576;            // 0..2047
        int f = q >> 6, l = q & 63;   // frag id (nt<4), lane
        int nt = f >> 3, kt = f & 7;
        int row = 16 * nt + (l & 15); // v index
        int k0 = 32 * kt + 8 * (l >> 4);
        unsigned short* ph = (unsigned short*)((char*)ws + 196608 + f * 1024 + l * 16);
        unsigned short* pl = (unsigned short*)((char*)ws + 229376 + f * 1024 + l * 16);
#pragma unroll
        for (int i = 0; i < 8; ++i) {
            float v = fc_w[row * HH + k0 + i];
            unsigned short hi = f2bf(v);
            float res = v - bf2f(hi);
            ph[i] = hi;
            pl[i] = f2bf(res);
        }
    }
}

__device__ __forceinline__ float tanh_fast(float x) {
    float a = fabsf(x);
    float e = __expf(-2.0f * a);
    float r = (1.0f - e) * __builtin_amdgcn_rcpf(1.0f + e);
    return copysignf(r, x);
}

__launch_bounds__(256, 1)
__global__ void rnn_kernel(const int* __restrict__ x,
                           const float* __restrict__ hidden,
                           const float* __restrict__ fc_b,
                           const float* __restrict__ ws,
                           float* __restrict__ out) {
    __shared__ __align__(16) unsigned short hb[2][HH];  // bf16 h, double buffered

    const int tid = threadIdx.x;
    const int b = blockIdx.x;
    const int w = tid >> 6;      // wave 0..3 (one per SIMD)
    const int l = tid & 63;

    const char* wsB  = (const char*)ws + 65536;
    const char* wsFH = (const char*)ws + 196608;
    const char* wsFL = (const char*)ws + 229376;
    const float* table = ws;

    float* outH = out + (size_t)BB * LL * VV;   // [B][H]

    // ---- register-resident weights ----
    bf16x8 Bf[4][8];                 // W_h for outputs [64w, 64w+64)
#pragma unroll
    for (int n = 0; n < 4; ++n)
#pragma unroll
        for (int k = 0; k < 8; ++k)
            Bf[n][k] = *(const bf16x8*)(wsB + (((4 * w + n) * 8 + k) * 1024) + l * 16);
    bf16x8 FH[8], FL[8];             // fc hi/lo for logits tile nt = w
#pragma unroll
    for (int k = 0; k < 8; ++k) {
        FH[k] = *(const bf16x8*)(wsFH + ((w * 8 + k) * 1024) + l * 16);
        FL[k] = *(const bf16x8*)(wsFL + ((w * 8 + k) * 1024) + l * 16);
    }
    const float fcb = fc_b[16 * w + (l & 15)];

    bf16x8 a[8];
    bf16x8 zz = {0, 0, 0, 0, 0, 0, 0, 0};
#pragma unroll
    for (int k = 0; k < 8; ++k) a[k] = zz;
    const int abyte = (l >> 4) * 16;

    if (tid < HH) hb[0][tid] = f2bf(hidden[b * HH + tid]);

    // xp pipeline
    const int xoff = l & 15;
    float xp[4];
    int xv_next;
    {
        int xv0 = x[b * LL];
#pragma unroll
        for (int n = 0; n < 4; ++n)
            xp[n] = table[xv0 * HH + 16 * (4 * w + n) + xoff];
        xv_next = x[b * LL + 1];
    }
    float lb[8];
    float* outLbase = out + (size_t)b * LL * VV + 16 * w + (l & 15);

    __syncthreads();

#pragma unroll 1
    for (int tb = 0; tb < LL; tb += 8) {
#pragma unroll
        for (int u = 0; u < 8; ++u) {
            const int t = tb + u;
            // ---- A-fragments: h_{t-1} (shared by matvec and logits) ----
            const char* hcur = (const char*)hb[u & 1];
            if ((l & 15) == 0) {
#pragma unroll
                for (int k = 0; k < 8; ++k)
                    a[k] = *(const bf16x8*)(hcur + k * 64 + abyte);
            }
            // ---- prefetch next xp / next-next token id ----
            float xpn[4];
            int xv3 = 0;
            if (t + 1 < LL) {
#pragma unroll
                for (int n = 0; n < 4; ++n)
                    xpn[n] = table[xv_next * HH + 16 * (4 * w + n) + xoff];
                xv3 = (t + 2 < LL) ? x[b * LL + t + 2] : 0;
            } else {
#pragma unroll
                for (int n = 0; n < 4; ++n) xpn[n] = 0.f;
            }

            // ---- logits for step t-1 (same A-frags; garbage at t==0, never stored) ----
            {
                f32x4 g0 = (f32x4){fcb, fcb, fcb, fcb};
                f32x4 g1 = (f32x4){0.f, 0.f, 0.f, 0.f};
                f32x4 r0 = (f32x4){0.f, 0.f, 0.f, 0.f};
                f32x4 r1 = (f32x4){0.f, 0.f, 0.f, 0.f};
#pragma unroll
                for (int k = 0; k < 4; ++k) {
                    g0 = __builtin_amdgcn_mfma_f32_16x16x32_bf16(a[k], FH[k], g0, 0, 0, 0);
                    g1 = __builtin_amdgcn_mfma_f32_16x16x32_bf16(a[4 + k], FH[4 + k], g1, 0, 0, 0);
                    r0 = __builtin_amdgcn_mfma_f32_16x16x32_bf16(a[k], FL[k], r0, 0, 0, 0);
                    r1 = __builtin_amdgcn_mfma_f32_16x16x32_bf16(a[4 + k], FL[4 + k], r1, 0, 0, 0);
                }
                lb[(u + 7) & 7] = (g0[0] + g1[0]) + (r0[0] + r1[0]);
            }

            // ---- matvec: 4 output tiles × 4 chains of depth 2 ----
            f32x4 c[4][4];
#pragma unroll
            for (int n = 0; n < 4; ++n) {
                c[n][0] = (f32x4){xp[n], xp[n], xp[n], xp[n]};
                c[n][1] = (f32x4){0.f, 0.f, 0.f, 0.f};
                c[n][2] = (f32x4){0.f, 0.f, 0.f, 0.f};
                c[n][3] = (f32x4){0.f, 0.f, 0.f, 0.f};
#pragma unroll
                for (int q = 0; q < 4; ++q) {
                    c[n][q] = __builtin_amdgcn_mfma_f32_16x16x32_bf16(a[2 * q], Bf[n][2 * q], c[n][q], 0, 0, 0);
                    c[n][q] = __builtin_amdgcn_mfma_f32_16x16x32_bf16(a[2 * q + 1], Bf[n][2 * q + 1], c[n][q], 0, 0, 0);
                }
            }

            // ---- flush 8 buffered logits once per 8 steps ----
            if (u == 0) {
                if (tb > 0 && l < 16) {
#pragma unroll
                    for (int k2 = 0; k2 < 8; ++k2)
                        outLbase[(size_t)(tb - 8 + k2) * VV] = lb[k2];
                }
            }

            // ---- merge, tanh, write h_t ----
            unsigned short* hnxt = hb[(u + 1) & 1];
#pragma unroll
            for (int n = 0; n < 4; ++n) {
                float s = (c[n][0][0] + c[n][1][0]) + (c[n][2][0] + c[n][3][0]);
                float hval = tanh_fast(s);
                if (l < 16) {
                    hnxt[16 * (4 * w + n) + l] = f2bf(hval);
                    if (u == 7 && tb == LL - 8)
                        outH[b * HH + 16 * (4 * w + n) + l] = hval;
                }
            }
#pragma unroll
            for (int n = 0; n < 4; ++n) xp[n] = xpn[n];
            xv_next = xv3;
            __syncthreads();
        }
    }

    // ---- epilogue: logits for step LL-1 from h_{LL-1} in hb[0] ----
    {
        const char* hcur = (const char*)hb[0];
        if ((l & 15) == 0) {
#pragma unroll
            for (int k = 0; k < 8; ++k)
                a[k] = *(const bf16x8*)(hcur + k * 64 + abyte);
        }
        f32x4 g0 = (f32x4){fcb, fcb, fcb, fcb};
        f32x4 g1 = (f32x4){0.f, 0.f, 0.f, 0.f};
        f32x4 r0 = (f32x4){0.f, 0.f, 0.f, 0.f};
        f32x4 r1 = (f32x4){0.f, 0.f, 0.f, 0.f};
#pragma unroll
        for (int k = 0; k < 4; ++k) {
            g0 = __builtin_amdgcn_mfma_f32_16x16x32_bf16(a[k], FH[k], g0, 0, 0, 0);
            g1 = __builtin_amdgcn_mfma_f32_16x16x32_bf16(a[4 + k], FH[4 + k], g1, 0, 0, 0);
            r0 = __builtin_amdgcn_mfma_f32_16x16x32_bf16(a[k], FL[k], r0, 0, 0, 0);
            r1 = __builtin_amdgcn_mfma_f32_16x16x32_bf16(a[4 + k], FL[4 + k], r1, 0, 0, 0);
        }
        lb[7] = (g0[0] + g1[0]) + (r0[0] + r1[0]);
        if (l < 16) {
#pragma unroll
            for (int k2 = 0; k2 < 8; ++k2)
                outLbase[(size_t)(LL - 8 + k2) * VV] = lb[k2];
        }
    }
}

extern "C" void kernel_launch(void* const* d_in, const int* in_sizes, int n_in,
                              void* d_out, int out_size, void* d_ws, size_t ws_size,
                              hipStream_t stream) {
    const int*   x      = (const int*)  d_in[0];
    const float* hidden = (const float*)d_in[1];
    const float* emb    = (const float*)d_in[2];
    const float* W_e    = (const float*)d_in[3];
    const float* b_e    = (const float*)d_in[4];
    const float* W_h    = (const float*)d_in[5];
    const float* b_h    = (const float*)d_in[6];
    const float* fc_w   = (const float*)d_in[7];
    const float* fc_b   = (const float*)d_in[8];
    float* out = (float*)d_out;
    float* ws  = (float*)d_ws;

    prep_kernel<<<104, 256, 0, stream>>>(emb, W_e, b_e, W_h, b_h, fc_w, ws);
    rnn_kernel<<<BB, 256, 0, stream>>>(x, hidden, fc_b, ws, out);
}

// Round 5
// 820.381 us; speedup vs baseline: 1.2147x; 1.2147x over previous
//
#include <hip/hip_runtime.h>
#include <hip/hip_bf16.h>

#define BB 256
#define LL 1024
#define EE 128
#define HH 256
#define VV 64

typedef short bf16x8 __attribute__((ext_vector_type(8)));
typedef float f32x4 __attribute__((ext_vector_type(4)));
typedef float v4f  __attribute__((ext_vector_type(4)));

// ws layout (bytes):
//   [0,      65536)   table f32 [64][256]: b_e[j]+b_h[j]+dot(emb[v],W_e[j])
//   [65536, 196608)   W_h B-frags bf16: frag f=nt*8+kt (nt<16,kt<8), 1024B each,
//                     elem (l,i) = W_h[16nt+(l&15)][32kt+8*(l>>4)+i]
//   [196608,229376)   fc hi frags (nt<4): fc_w[16nt+(l&15)][32kt+8*(l>>4)+i] hi
//   [229376,262144)   fc lo frags (residual)

__device__ __forceinline__ unsigned short f2bf(float v) {
    __hip_bfloat16 h = __float2bfloat16(v);
    return *reinterpret_cast<unsigned short*>(&h);
}
__device__ __forceinline__ float bf2f(unsigned short u) {
    __hip_bfloat16 h = *reinterpret_cast<__hip_bfloat16*>(&u);
    return __bfloat162float(h);
}

__global__ void prep_kernel(const float* __restrict__ emb,
                            const float* __restrict__ W_e,
                            const float* __restrict__ b_e,
                            const float* __restrict__ W_h,
                            const float* __restrict__ b_h,
                            const float* __restrict__ fc_w,
                            float* __restrict__ ws) {
    int t = blockIdx.x * 256 + threadIdx.x;  // 0..26623
    if (t < 16384) {
        int v = t >> 8, j = t & 255;
        float s = b_e[j] + b_h[j];
        const v4f* ev = (const v4f*)(emb + v * EE);
        const v4f* wr = (const v4f*)(W_e + j * EE);
#pragma unroll
        for (int e = 0; e < EE / 4; ++e) {
            v4f a = ev[e], c = wr[e];
            s += a.x * c.x + a.y * c.y + a.z * c.z + a.w * c.w;
        }
        ws[t] = s;
    } else if (t < 24576) {
        int q = t - 16384;            // 0..8191
        int f = q >> 6, l = q & 63;   // frag id, lane
        int nt = f >> 3, kt = f & 7;
        int row = 16 * nt + (l & 15);
        int k0 = 32 * kt + 8 * (l >> 4);
        unsigned short* p = (unsigned short*)((char*)ws + 65536 + f * 1024 + l * 16);
#pragma unroll
        for (int i = 0; i < 8; ++i) p[i] = f2bf(W_h[row * HH + k0 + i]);
    } else {
        int q = t - 24576;            // 0..2047
        int f = q >> 6, l = q & 63;   // frag id (nt<4), lane
        int nt = f >> 3, kt = f & 7;
        int row = 16 * nt + (l & 15); // v index
        int k0 = 32 * kt + 8 * (l >> 4);
        unsigned short* ph = (unsigned short*)((char*)ws + 196608 + f * 1024 + l * 16);
        unsigned short* pl = (unsigned short*)((char*)ws + 229376 + f * 1024 + l * 16);
#pragma unroll
        for (int i = 0; i < 8; ++i) {
            float v = fc_w[row * HH + k0 + i];
            unsigned short hi = f2bf(v);
            float res = v - bf2f(hi);
            ph[i] = hi;
            pl[i] = f2bf(res);
        }
    }
}

__device__ __forceinline__ float tanh_fast(float x) {
    float a = fabsf(x);
    float e = __expf(-2.0f * a);
    float r = (1.0f - e) * __builtin_amdgcn_rcpf(1.0f + e);
    return copysignf(r, x);
}

// Raw per-step barrier: NO vmcnt drain (global stores stream free).
// lgkmcnt(0) makes this wave's ds_writes visible before the barrier;
// sched_barriers stop hipcc hoisting/sinking memory ops across it.
__device__ __forceinline__ void step_barrier() {
    asm volatile("s_waitcnt lgkmcnt(0)" ::: "memory");
    __builtin_amdgcn_sched_barrier(0);
    __builtin_amdgcn_s_barrier();
    __builtin_amdgcn_sched_barrier(0);
}

__launch_bounds__(512, 1)
__global__ void rnn_kernel(const int* __restrict__ x,
                           const float* __restrict__ hidden,
                           const float* __restrict__ fc_b,
                           const float* __restrict__ ws,
                           float* __restrict__ out) {
    __shared__ __align__(16) unsigned short hb[2][HH];  // bf16 h double buffer, 1 KB

    const int tid = threadIdx.x;
    const int b = blockIdx.x;
    const int w = tid >> 6;      // wave 0..7 (SIMD = w&3: 1 recur + 1 logits each)
    const int l = tid & 63;

    const char* wsB  = (const char*)ws + 65536;
    const char* wsFH = (const char*)ws + 196608;
    const char* wsFL = (const char*)ws + 229376;
    const float* table = ws;

    float* outH = out + (size_t)BB * LL * VV;   // [B][H]

    if (tid < HH) hb[0][tid] = f2bf(hidden[b * HH + tid]);

    bf16x8 a[8];
    bf16x8 zz = {0, 0, 0, 0, 0, 0, 0, 0};
#pragma unroll
    for (int k = 0; k < 8; ++k) a[k] = zz;
    const int abyte = (l >> 4) * 16;

    __syncthreads();

    if (w < 4) {
        // ================= recurrence role: outputs [64w, 64w+64) =================
        bf16x8 Bf[4][8];
#pragma unroll
        for (int n = 0; n < 4; ++n)
#pragma unroll
            for (int k = 0; k < 8; ++k)
                Bf[n][k] = *(const bf16x8*)(wsB + (((4 * w + n) * 8 + k) * 1024) + l * 16);

        const int xoff = l & 15;
        float xp[4];
        int xv_next;
        {
            int xv0 = x[b * LL];
#pragma unroll
            for (int n = 0; n < 4; ++n)
                xp[n] = table[xv0 * HH + 16 * (4 * w + n) + xoff];
            xv_next = x[b * LL + 1];
        }

#pragma unroll 1
        for (int t = 0; t <= LL; ++t) {
            if (t < LL) {
                const char* hcur = (const char*)hb[t & 1];
                if ((l & 15) == 0) {
#pragma unroll
                    for (int k = 0; k < 8; ++k)
                        a[k] = *(const bf16x8*)(hcur + k * 64 + abyte);
                }
                // prefetch next xp / token
                float xpn[4];
                int xv3 = 0;
                if (t + 1 < LL) {
#pragma unroll
                    for (int n = 0; n < 4; ++n)
                        xpn[n] = table[xv_next * HH + 16 * (4 * w + n) + xoff];
                    xv3 = (t + 2 < LL) ? x[b * LL + t + 2] : 0;
                } else {
#pragma unroll
                    for (int n = 0; n < 4; ++n) xpn[n] = 0.f;
                }

                unsigned short* hnxt = hb[(t + 1) & 1];
#pragma unroll
                for (int n = 0; n < 4; ++n) {
                    f32x4 c0 = (f32x4){xp[n], xp[n], xp[n], xp[n]};
                    f32x4 c1 = (f32x4){0.f, 0.f, 0.f, 0.f};
#pragma unroll
                    for (int q = 0; q < 4; ++q) {
                        c0 = __builtin_amdgcn_mfma_f32_16x16x32_bf16(a[q], Bf[n][q], c0, 0, 0, 0);
                        c1 = __builtin_amdgcn_mfma_f32_16x16x32_bf16(a[4 + q], Bf[n][4 + q], c1, 0, 0, 0);
                    }
                    float hval = tanh_fast(c0[0] + c1[0]);
                    if (l < 16) {
                        hnxt[16 * (4 * w + n) + l] = f2bf(hval);
                        if (t == LL - 1)
                            outH[b * HH + 16 * (4 * w + n) + l] = hval;
                    }
                }
#pragma unroll
                for (int n = 0; n < 4; ++n) xp[n] = xpn[n];
                xv_next = xv3;
            }
            step_barrier();
        }
    } else {
        // ================= logits role: v-outputs [16(w-4), 16(w-4)+16) =================
        const int nt = w - 4;
        bf16x8 FH[8], FL[8];
#pragma unroll
        for (int k = 0; k < 8; ++k) {
            FH[k] = *(const bf16x8*)(wsFH + ((nt * 8 + k) * 1024) + l * 16);
            FL[k] = *(const bf16x8*)(wsFL + ((nt * 8 + k) * 1024) + l * 16);
        }
        const float fcb = fc_b[16 * nt + (l & 15)];
        float lb[8];
        float* outLbase = out + (size_t)b * LL * VV + 16 * nt + (l & 15);

        step_barrier();  // t = 0 (no logits work)

#pragma unroll 1
        for (int tb = 1; tb < LL; tb += 8) {
#pragma unroll
            for (int u = 0; u < 8; ++u) {
                const int t = tb + u;         // 1..1024
                const char* hcur = (const char*)hb[t & 1];   // h_{t-1}
                if ((l & 15) == 0) {
#pragma unroll
                    for (int k = 0; k < 8; ++k)
                        a[k] = *(const bf16x8*)(hcur + k * 64 + abyte);
                }
                f32x4 g0 = (f32x4){fcb, fcb, fcb, fcb};
                f32x4 g1 = (f32x4){0.f, 0.f, 0.f, 0.f};
                f32x4 r0 = (f32x4){0.f, 0.f, 0.f, 0.f};
                f32x4 r1 = (f32x4){0.f, 0.f, 0.f, 0.f};
#pragma unroll
                for (int q = 0; q < 4; ++q) {
                    g0 = __builtin_amdgcn_mfma_f32_16x16x32_bf16(a[q], FH[q], g0, 0, 0, 0);
                    g1 = __builtin_amdgcn_mfma_f32_16x16x32_bf16(a[4 + q], FH[4 + q], g1, 0, 0, 0);
                    r0 = __builtin_amdgcn_mfma_f32_16x16x32_bf16(a[q], FL[q], r0, 0, 0, 0);
                    r1 = __builtin_amdgcn_mfma_f32_16x16x32_bf16(a[4 + q], FL[4 + q], r1, 0, 0, 0);
                }
                lb[u] = (g0[0] + g1[0]) + (r0[0] + r1[0]);   // logits step t-1 (= tb-1+u)
                if (u == 7 && l < 16) {
#pragma unroll
                    for (int k2 = 0; k2 < 8; ++k2)
                        outLbase[(size_t)(tb - 1 + k2) * VV] = lb[k2];
                }
                step_barrier();
            }
        }
    }
}

extern "C" void kernel_launch(void* const* d_in, const int* in_sizes, int n_in,
                              void* d_out, int out_size, void* d_ws, size_t ws_size,
                              hipStream_t stream) {
    const int*   x      = (const int*)  d_in[0];
    const float* hidden = (const float*)d_in[1];
    const float* emb    = (const float*)d_in[2];
    const float* W_e    = (const float*)d_in[3];
    const float* b_e    = (const float*)d_in[4];
    const float* W_h    = (const float*)d_in[5];
    const float* b_h    = (const float*)d_in[6];
    const float* fc_w   = (const float*)d_in[7];
    const float* fc_b   = (const float*)d_in[8];
    float* out = (float*)d_out;
    float* ws  = (float*)d_ws;

    prep_kernel<<<104, 256, 0, stream>>>(emb, W_e, b_e, W_h, b_h, fc_w, ws);
    rnn_kernel<<<BB, 512, 0, stream>>>(x, hidden, fc_b, ws, out);
}

// Round 6
// 799.489 us; speedup vs baseline: 1.2464x; 1.0261x over previous
//
#include <hip/hip_runtime.h>
#include <hip/hip_bf16.h>

#define BB 256
#define LL 1024
#define EE 128
#define HH 256
#define VV 64

typedef short bf16x8 __attribute__((ext_vector_type(8)));
typedef float f32x4 __attribute__((ext_vector_type(4)));
typedef float v4f  __attribute__((ext_vector_type(4)));

// ws layout (bytes):
//   [0,      65536)   table f32 [64][256]: b_e[j]+b_h[j]+dot(emb[v],W_e[j])
//   [65536, 196608)   W_h B-frags bf16: frag f=nt*8+kt (nt<16,kt<8), 1024B each,
//                     elem (l,i) = W_h[16nt+(l&15)][32kt+8*(l>>4)+i]
//   [196608,229376)   fc hi frags (nt<4): fc_w[16nt+(l&15)][32kt+8*(l>>4)+i] hi
//   [229376,262144)   fc lo frags (residual)

__device__ __forceinline__ unsigned short f2bf(float v) {
    __hip_bfloat16 h = __float2bfloat16(v);
    return *reinterpret_cast<unsigned short*>(&h);
}
__device__ __forceinline__ float bf2f(unsigned short u) {
    __hip_bfloat16 h = *reinterpret_cast<__hip_bfloat16*>(&u);
    return __bfloat162float(h);
}

__global__ void prep_kernel(const float* __restrict__ emb,
                            const float* __restrict__ W_e,
                            const float* __restrict__ b_e,
                            const float* __restrict__ W_h,
                            const float* __restrict__ b_h,
                            const float* __restrict__ fc_w,
                            float* __restrict__ ws) {
    int t = blockIdx.x * 256 + threadIdx.x;  // 0..26623
    if (t < 16384) {
        int v = t >> 8, j = t & 255;
        float s = b_e[j] + b_h[j];
        const v4f* ev = (const v4f*)(emb + v * EE);
        const v4f* wr = (const v4f*)(W_e + j * EE);
#pragma unroll
        for (int e = 0; e < EE / 4; ++e) {
            v4f a = ev[e], c = wr[e];
            s += a.x * c.x + a.y * c.y + a.z * c.z + a.w * c.w;
        }
        ws[t] = s;
    } else if (t < 24576) {
        int q = t - 16384;            // 0..8191
        int f = q >> 6, l = q & 63;   // frag id, lane
        int nt = f >> 3, kt = f & 7;
        int row = 16 * nt + (l & 15);
        int k0 = 32 * kt + 8 * (l >> 4);
        unsigned short* p = (unsigned short*)((char*)ws + 65536 + f * 1024 + l * 16);
#pragma unroll
        for (int i = 0; i < 8; ++i) p[i] = f2bf(W_h[row * HH + k0 + i]);
    } else {
        int q = t - 24576;            // 0..2047
        int f = q >> 6, l = q & 63;   // frag id (nt<4), lane
        int nt = f >> 3, kt = f & 7;
        int row = 16 * nt + (l & 15); // v index
        int k0 = 32 * kt + 8 * (l >> 4);
        unsigned short* ph = (unsigned short*)((char*)ws + 196608 + f * 1024 + l * 16);
        unsigned short* pl = (unsigned short*)((char*)ws + 229376 + f * 1024 + l * 16);
#pragma unroll
        for (int i = 0; i < 8; ++i) {
            float v = fc_w[row * HH + k0 + i];
            unsigned short hi = f2bf(v);
            float res = v - bf2f(hi);
            ph[i] = hi;
            pl[i] = f2bf(res);
        }
    }
}

__device__ __forceinline__ float tanh_fast(float x) {
    float a = fabsf(x);
    float e = __expf(-2.0f * a);
    float r = (1.0f - e) * __builtin_amdgcn_rcpf(1.0f + e);
    return copysignf(r, x);
}

// MFMA with operands FORCE-PINNED to arch VGPRs ("v" constraints): the
// compiler otherwise parks B-frags in AGPRs, and AGPR-sourced MFMA runs at
// ~17 cyc/instr (R5 counters) vs ~5 for VGPR-sourced.
__device__ __forceinline__ void mfma16(f32x4& c, bf16x8 a, bf16x8 b) {
    asm("v_mfma_f32_16x16x32_bf16 %0, %1, %2, %0" : "+v"(c) : "v"(a), "v"(b));
}

// Raw per-step barrier: NO vmcnt drain (logits stores stream free).
__device__ __forceinline__ void step_barrier() {
    asm volatile("s_waitcnt lgkmcnt(0)" ::: "memory");
    __builtin_amdgcn_sched_barrier(0);
    __builtin_amdgcn_s_barrier();
    __builtin_amdgcn_sched_barrier(0);
}

__launch_bounds__(512, 1)
__global__ void rnn_kernel(const int* __restrict__ x,
                           const float* __restrict__ hidden,
                           const float* __restrict__ fc_b,
                           const float* __restrict__ ws,
                           float* __restrict__ out) {
    __shared__ __align__(16) unsigned short hb[2][HH];  // bf16 h double buffer, 1 KB

    const int tid = threadIdx.x;
    const int b = blockIdx.x;
    const int w = tid >> 6;      // wave 0..7 (SIMD = w&3: 1 recur + 1 logits each)
    const int l = tid & 63;

    const char* wsB  = (const char*)ws + 65536;
    const char* wsFH = (const char*)ws + 196608;
    const char* wsFL = (const char*)ws + 229376;
    const float* table = ws;

    float* outH = out + (size_t)BB * LL * VV;   // [B][H]

    if (tid < HH) hb[0][tid] = f2bf(hidden[b * HH + tid]);

    bf16x8 a[8];
    const int abyte = (l >> 4) * 16;   // all-lane broadcast chunk (16 lanes/addr)

    __syncthreads();

    if (w < 4) {
        // ================= recurrence role: outputs [64w, 64w+64) =================
        __builtin_amdgcn_s_setprio(1);   // critical wave: win issue arbitration
        bf16x8 Bf[4][8];
#pragma unroll
        for (int n = 0; n < 4; ++n)
#pragma unroll
            for (int k = 0; k < 8; ++k)
                Bf[n][k] = *(const bf16x8*)(wsB + (((4 * w + n) * 8 + k) * 1024) + l * 16);

        const int xoff = l & 15;
        float xp[4];
        int xv_next;
        {
            int xv0 = x[b * LL];
#pragma unroll
            for (int n = 0; n < 4; ++n)
                xp[n] = table[xv0 * HH + 16 * (4 * w + n) + xoff];
            xv_next = x[b * LL + 1];
        }

#pragma unroll 1
        for (int t = 0; t <= LL; ++t) {
            if (t < LL) {
                const char* hcur = (const char*)hb[t & 1];
#pragma unroll
                for (int k = 0; k < 8; ++k)
                    a[k] = *(const bf16x8*)(hcur + k * 64 + abyte);

                // prefetch next xp / token
                float xpn[4];
                int xv3 = 0;
                if (t + 1 < LL) {
#pragma unroll
                    for (int n = 0; n < 4; ++n)
                        xpn[n] = table[xv_next * HH + 16 * (4 * w + n) + xoff];
                    xv3 = (t + 2 < LL) ? x[b * LL + t + 2] : 0;
                } else {
#pragma unroll
                    for (int n = 0; n < 4; ++n) xpn[n] = 0.f;
                }

                f32x4 c0[4], c1[4];
#pragma unroll
                for (int n = 0; n < 4; ++n) {
                    c0[n] = (f32x4){xp[n], xp[n], xp[n], xp[n]};
                    c1[n] = (f32x4){0.f, 0.f, 0.f, 0.f};
                }
                // 8 independent chains, reuse distance 8 (covers MFMA latency)
#pragma unroll
                for (int q = 0; q < 4; ++q) {
#pragma unroll
                    for (int n = 0; n < 4; ++n) mfma16(c0[n], a[q], Bf[n][q]);
#pragma unroll
                    for (int n = 0; n < 4; ++n) mfma16(c1[n], a[4 + q], Bf[n][4 + q]);
                }

                unsigned short* hnxt = hb[(t + 1) & 1];
#pragma unroll
                for (int n = 0; n < 4; ++n) {
                    float hval = tanh_fast(c0[n][0] + c1[n][0]);
                    if (l < 16) {
                        hnxt[16 * (4 * w + n) + l] = f2bf(hval);
                        if (t == LL - 1)
                            outH[b * HH + 16 * (4 * w + n) + l] = hval;
                    }
                }
#pragma unroll
                for (int n = 0; n < 4; ++n) xp[n] = xpn[n];
                xv_next = xv3;
            }
            step_barrier();
        }
    } else {
        // ================= logits role: v-outputs [16(w-4), 16(w-4)+16) =================
        const int nt = w - 4;
        bf16x8 FH[8], FL[8];
#pragma unroll
        for (int k = 0; k < 8; ++k) {
            FH[k] = *(const bf16x8*)(wsFH + ((nt * 8 + k) * 1024) + l * 16);
            FL[k] = *(const bf16x8*)(wsFL + ((nt * 8 + k) * 1024) + l * 16);
        }
        const float fcb = fc_b[16 * nt + (l & 15)];
        float lb[8];
        float* outLbase = out + (size_t)b * LL * VV + 16 * nt + (l & 15);

        step_barrier();  // t = 0 (no logits work)

#pragma unroll 1
        for (int tb = 1; tb < LL; tb += 8) {
#pragma unroll
            for (int u = 0; u < 8; ++u) {
                const int t = tb + u;         // 1..1024
                const char* hcur = (const char*)hb[t & 1];   // h_{t-1}
#pragma unroll
                for (int k = 0; k < 8; ++k)
                    a[k] = *(const bf16x8*)(hcur + k * 64 + abyte);

                f32x4 g0 = (f32x4){fcb, fcb, fcb, fcb};
                f32x4 g1 = (f32x4){0.f, 0.f, 0.f, 0.f};
                f32x4 r0 = (f32x4){0.f, 0.f, 0.f, 0.f};
                f32x4 r1 = (f32x4){0.f, 0.f, 0.f, 0.f};
#pragma unroll
                for (int q = 0; q < 4; ++q) {
                    mfma16(g0, a[q], FH[q]);
                    mfma16(g1, a[4 + q], FH[4 + q]);
                    mfma16(r0, a[q], FL[q]);
                    mfma16(r1, a[4 + q], FL[4 + q]);
                }
                lb[u] = (g0[0] + g1[0]) + (r0[0] + r1[0]);   // logits step t-1
                if (u == 7 && l < 16) {
#pragma unroll
                    for (int k2 = 0; k2 < 8; ++k2)
                        outLbase[(size_t)(tb - 1 + k2) * VV] = lb[k2];
                }
                step_barrier();
            }
        }
    }
}

extern "C" void kernel_launch(void* const* d_in, const int* in_sizes, int n_in,
                              void* d_out, int out_size, void* d_ws, size_t ws_size,
                              hipStream_t stream) {
    const int*   x      = (const int*)  d_in[0];
    const float* hidden = (const float*)d_in[1];
    const float* emb    = (const float*)d_in[2];
    const float* W_e    = (const float*)d_in[3];
    const float* b_e    = (const float*)d_in[4];
    const float* W_h    = (const float*)d_in[5];
    const float* b_h    = (const float*)d_in[6];
    const float* fc_w   = (const float*)d_in[7];
    const float* fc_b   = (const float*)d_in[8];
    float* out = (float*)d_out;
    float* ws  = (float*)d_ws;

    prep_kernel<<<104, 256, 0, stream>>>(emb, W_e, b_e, W_h, b_h, fc_w, ws);
    rnn_kernel<<<BB, 512, 0, stream>>>(x, hidden, fc_b, ws, out);
}